// Round 8
// baseline (116.938 us; speedup 1.0000x reference)
//
#include <hip/hip_runtime.h>

// S4D via chunked MFMA reformulation, fused A+B+C (R7 = R6 + compile fix).
//
//  y[c*64+t] = sum_j k[t-j]*x[c*64+j]              (lower-tri Toeplitz, local)
//            + Re( sum_n Ceff2_n w_n^{t+1} S_n[c] ) (carry from prior chunks)
//  S_n[c]    = w^64 * S_n[c-1] + V_n[c-1],  V_n[c] = sum_j w_n^{63-j} x[c*64+j]
//
//  prep : per h, bf16 matrices in global ws (L2-resident).
//  fused: grid 1024 = (h, b-pair), block 256 = 4 waves; each wave owns
//         16 (chunk) cols of one batch (half a scan row):
//    A: MFMA V = X*W1^T (complex) -> packed LDS (stride-68 uints, 2-way)
//    B: two-level scan: low half scans from 0, publishes fp32 carry T via
//       LDS; high half re-scans its reg-held V's from init=T. Entering
//       states -> r/i ushort planes (144 B rows: aligned b128, <=2-way).
//    C: S-frags = plain ds_read_b128; y = Xhi*TL+Xlo*TL+Sr*W2r+Si*W2i, relu.
//  Blocks sharing h are 256 apart in blockIdx -> same XCD (bid mod 8) for
//  W-matrix L2 reuse.

#define B_ 8
#define H_ 256
#define N_ 64
#define L_ 2048
#define Q_ 64
#define NC_ 32
#define HC_ 16         // chunks per wave (half scan row)
#define PKSTR_ 68      // packed V row stride (uints)
#define PLSTR_ 72      // plane row stride (ushorts); 144 B rows, 16B-aligned

typedef __attribute__((ext_vector_type(8))) short bf16x8;
typedef __attribute__((ext_vector_type(4))) float f32x4;

// ---- ws layout (bytes): 5 bf16 matrices, 2 MiB each ----
#define WS_W1R  0
#define WS_W1I  (WS_W1R + 2097152)
#define WS_TL   (WS_W1I + 2097152)
#define WS_W2R  (WS_TL  + 2097152)
#define WS_W2I  (WS_W2R + 2097152)

#if defined(__has_builtin)
#  if __has_builtin(__builtin_amdgcn_cvt_pk_bf16_f32)
#    define HAVE_CVT_PK 1
#  endif
#endif

__device__ __forceinline__ unsigned short bf16_rne(float f) {
    unsigned int u = __float_as_uint(f);
    u += 0x7FFF + ((u >> 16) & 1);
    return (unsigned short)(u >> 16);
}
__device__ __forceinline__ float bf16_to_f(unsigned short h) {
    return __uint_as_float(((unsigned int)h) << 16);
}
// pack two floats to bf16x2 (a -> low, b -> high), RNE
__device__ __forceinline__ unsigned int pack_bf16x2(float a, float b) {
#ifdef HAVE_CVT_PK
    typedef __bf16 bf16v2 __attribute__((ext_vector_type(2)));
    bf16v2 p = __builtin_amdgcn_cvt_pk_bf16_f32(a, b);
    return __builtin_bit_cast(unsigned int, p);
#else
    unsigned int ua = __float_as_uint(a);
    ua += 0x7FFF + ((ua >> 16) & 1);
    unsigned int ub = __float_as_uint(b);
    ub += 0x7FFF + ((ub >> 16) & 1);
    return (ua >> 16) | (ub & 0xFFFF0000u);
#endif
}

// ================= prep: per-h parameter matrices (global) =================
__global__ __launch_bounds__(64) void s4d_prep(
    const float* __restrict__ A_real, const float* __restrict__ A_imag,
    const float* __restrict__ Bmat, const float* __restrict__ Cmat,
    const float* __restrict__ inv_dt,
    unsigned short* __restrict__ W1sr, unsigned short* __restrict__ W1si,
    unsigned short* __restrict__ TLs,
    unsigned short* __restrict__ W2sr, unsigned short* __restrict__ W2si)
{
    __shared__ float lds[64 * 68];
    __shared__ float klds[64];

    const int h = blockIdx.x;
    const int n = threadIdx.x;
    const int hn = h * N_ + n;

    const float Ar = -expf(A_real[hn]);     // A = -exp(A_real) - i*A_imag
    const float Ai = -A_imag[hn];
    const float dtv = expf(inv_dt[h]);
    const float dr = dtv * Ar;
    const float di = dtv * Ai;
    const float ew = expf(dr);
    float sdi, cdi;
    sincosf(di, &sdi, &cdi);
    const float wr = ew * cdi;              // w = exp(dt*A)
    const float wi = ew * sdi;
    const float em1r = wr - 1.0f;           // (w-1)/A
    const float em1i = wi;
    const float invden = 1.0f / (Ar * Ar + Ai * Ai);
    const float tr = (em1r * Ar + em1i * Ai) * invden;
    const float ti = (em1i * Ar - em1r * Ai) * invden;
    const float br = Bmat[2 * hn], bi = Bmat[2 * hn + 1];
    const float cr = Cmat[2 * hn], ci = Cmat[2 * hn + 1];
    const float bcr = br * cr - bi * ci;
    const float bci = br * ci + bi * cr;
    const float Cr = 2.0f * (bcr * tr - bci * ti);   // Ceff2 = 2*B*C*(w-1)/A
    const float Ci = 2.0f * (bcr * ti + bci * tr);

    unsigned short* w1r = W1sr + h * 4096;
    unsigned short* w1i = W1si + h * 4096;
    unsigned short* w2r = W2sr + h * 4096;
    unsigned short* w2i = W2si + h * 4096;

    float pr = 1.0f, pi = 0.0f;             // w^m
    for (int m = 0; m <= 64; ++m) {
        const float qr = Cr * pr - Ci * pi; // Re(Ceff2 * w^m)
        const float qi = Cr * pi + Ci * pr;
        if (m < 64) {
            lds[m * 68 + n] = qr;
            w1r[n * 64 + (63 - m)] = bf16_rne(pr);   // W1s[n][j]=w^(63-j)
            w1i[n * 64 + (63 - m)] = bf16_rne(pi);
        }
        if (m >= 1) {
            w2r[(m - 1) * 64 + n] = bf16_rne(qr);    // Re(Ceff2*w^(t+1))
            w2i[(m - 1) * 64 + n] = bf16_rne(-qi);   // -Im(...)
        }
        const float npr = pr * wr - pi * wi;
        pi = pr * wi + pi * wr;
        pr = npr;
    }
    __syncthreads();

    // k[t] = sum_n Re(Ceff2 * w_n^t)
    float s = 0.0f;
    for (int m = 0; m < 64; ++m) s += lds[n * 68 + m];
    klds[n] = s;
    __syncthreads();

    // TLs[t][j] = (j<=t) ? k[t-j] : 0   (lane = j)
    unsigned short* tl = TLs + h * 4096;
    for (int t = 0; t < 64; ++t) {
        const int d = t - n;
        const float kv = (d >= 0) ? klds[d >= 0 ? d : 0] : 0.0f;
        tl[t * 64 + n] = bf16_rne(kv);
    }
}

// ================= fused: V-GEMM -> split in-LDS scan -> y-GEMM =================
__global__ __launch_bounds__(256) void s4d_fused(
    const float* __restrict__ x,
    const float* __restrict__ A_real, const float* __restrict__ A_imag,
    const float* __restrict__ inv_dt,
    const unsigned short* __restrict__ W1sr, const unsigned short* __restrict__ W1si,
    const unsigned short* __restrict__ TLs,
    const unsigned short* __restrict__ W2sr, const unsigned short* __restrict__ W2si,
    float* __restrict__ out)
{
    // region 0..18432: packed V (64x68 uints = 17408 B) aliased with the two
    // state planes (2 x 64x72 ushorts = 18432 B); barrier separates lifetimes.
    // region 18432..19456: fp32 carry exchange Tx[2*64] (flat indexed).
    __shared__ char smem[19456];
    unsigned int*   vpk = (unsigned int*)smem;
    unsigned short* spr = (unsigned short*)smem;
    unsigned short* spi = (unsigned short*)(smem + 9216);
    float2*         Tx  = (float2*)(smem + 18432);

    const int h    = blockIdx.x & (H_ - 1);      // blocks sharing h: same XCD
    const int bp   = blockIdx.x >> 8;            // 0..3 batch pair
    const int lane = threadIdx.x & 63;
    const int wv   = threadIdx.x >> 6;           // 0..3
    const int b    = bp * 2 + (wv >> 1);
    const int half = wv & 1;                     // which 16-chunk half
    const int l15  = lane & 15;
    const int quad = lane >> 4;
    const int rowb = wv * 16;                    // block-local col base

    // ---- x fragments (one 16-col M-tile), hi/lo bf16 split ----
    bf16x8 xhi[2], xlo[2];
    {
        const float* xp = x + ((size_t)(b * H_ + h)) * L_ + (half * HC_ + l15) * Q_;
        #pragma unroll
        for (int kk = 0; kk < 2; ++kk) {
            const int j0 = kk * 32 + quad * 8;
            const float4 f0 = *(const float4*)(xp + j0);
            const float4 f1 = *(const float4*)(xp + j0 + 4);
            float f[8] = {f0.x, f0.y, f0.z, f0.w, f1.x, f1.y, f1.z, f1.w};
            union { unsigned int u[4]; bf16x8 v; } hi, lo;
            #pragma unroll
            for (int p = 0; p < 4; ++p) {
                const unsigned int hp = pack_bf16x2(f[2 * p], f[2 * p + 1]);
                hi.u[p] = hp;
                const float h0 = __uint_as_float(hp << 16);
                const float h1 = __uint_as_float(hp & 0xFFFF0000u);
                lo.u[p] = pack_bf16x2(f[2 * p] - h0, f[2 * p + 1] - h1);
            }
            xhi[kk] = hi.v;
            xlo[kk] = lo.v;
        }
    }

    // ---- per-thread E = w^64 for n = lane ----
    float Er, Ei;
    {
        const int hn = h * N_ + lane;
        const float Ar = -expf(A_real[hn]);
        const float Ai = -A_imag[hn];
        const float dtv = expf(inv_dt[h]);
        const float e64 = expf(64.0f * dtv * Ar);
        float s64, c64;
        sincosf(64.0f * dtv * Ai, &s64, &c64);
        Er = e64 * c64;
        Ei = e64 * s64;
    }

    // ---- phase A: V = X * W1^T (complex) -> packed LDS ----
    {
        const unsigned short* w1r = W1sr + h * 4096;
        const unsigned short* w1i = W1si + h * 4096;

        f32x4 accr[4], acci[4];
        #pragma unroll
        for (int nt = 0; nt < 4; ++nt) { accr[nt] = (f32x4)0.0f; acci[nt] = (f32x4)0.0f; }

        #pragma unroll
        for (int nt = 0; nt < 4; ++nt) {
            const int n = nt * 16 + l15;
            #pragma unroll
            for (int kk = 0; kk < 2; ++kk) {
                const int j0 = kk * 32 + quad * 8;
                const bf16x8 brf = *(const bf16x8*)(w1r + n * 64 + j0);
                const bf16x8 bif = *(const bf16x8*)(w1i + n * 64 + j0);
                accr[nt] = __builtin_amdgcn_mfma_f32_16x16x32_bf16(
                    xhi[kk], brf, accr[nt], 0, 0, 0);
                acci[nt] = __builtin_amdgcn_mfma_f32_16x16x32_bf16(
                    xhi[kk], bif, acci[nt], 0, 0, 0);
            }
        }

        // D layout: row=(quad*4+r) -> local col, col=l15 -> n
        #pragma unroll
        for (int nt = 0; nt < 4; ++nt)
            #pragma unroll
            for (int r = 0; r < 4; ++r) {
                const int row = rowb + quad * 4 + r;
                const int n   = nt * 16 + l15;
                vpk[row * PKSTR_ + n] = pack_bf16x2(accr[nt][r], acci[nt][r]);
            }
    }
    __syncthreads();

    // ---- phase B: split scan with fp32 carry exchange ----
    {
        unsigned int vv[HC_];
        #pragma unroll
        for (int c = 0; c < HC_; ++c) vv[c] = vpk[(rowb + c) * PKSTR_ + lane];
        __syncthreads();                       // packed lifetime ends

        float sr = 0.0f, si = 0.0f;
        if (half == 0) {                       // low half: scan from 0
            #pragma unroll
            for (int c = 0; c < HC_; ++c) {
                const float vr = __uint_as_float(vv[c] << 16);
                const float vi = __uint_as_float(vv[c] & 0xFFFF0000u);
                const unsigned int sp2 = pack_bf16x2(sr, si);
                spr[(rowb + c) * PLSTR_ + lane] = (unsigned short)(sp2 & 0xFFFFu);
                spi[(rowb + c) * PLSTR_ + lane] = (unsigned short)(sp2 >> 16);
                const float nsr = fmaf(Er, sr, fmaf(-Ei, si, vr));
                si = fmaf(Ei, sr, fmaf(Er, si, vi));
                sr = nsr;
            }
            Tx[(wv >> 1) * 64 + lane] = make_float2(sr, si);  // carry -> high half
        }
        __syncthreads();
        if (half == 1) {                       // high half: scan from T
            const float2 T = Tx[(wv >> 1) * 64 + lane];
            sr = T.x; si = T.y;
            #pragma unroll
            for (int c = 0; c < HC_; ++c) {
                const float vr = __uint_as_float(vv[c] << 16);
                const float vi = __uint_as_float(vv[c] & 0xFFFF0000u);
                const unsigned int sp2 = pack_bf16x2(sr, si);
                spr[(rowb + c) * PLSTR_ + lane] = (unsigned short)(sp2 & 0xFFFFu);
                spi[(rowb + c) * PLSTR_ + lane] = (unsigned short)(sp2 >> 16);
                const float nsr = fmaf(Er, sr, fmaf(-Ei, si, vr));
                si = fmaf(Ei, sr, fmaf(Er, si, vi));
                sr = nsr;
            }
        }
    }
    __syncthreads();

    // ---- phase C: y = Xhi*TL + Xlo*TL + Sr*W2r + Si*W2i, relu ----
    {
        const unsigned short* tl  = TLs  + h * 4096;
        const unsigned short* w2r = W2sr + h * 4096;
        const unsigned short* w2i = W2si + h * 4096;

        // S fragments: plain b128 reads from planes (A-operand layout)
        bf16x8 sr8[2], si8[2];
        #pragma unroll
        for (int kk = 0; kk < 2; ++kk) {
            const int j0 = kk * 32 + quad * 8;
            sr8[kk] = *(const bf16x8*)(&spr[(rowb + l15) * PLSTR_ + j0]);
            si8[kk] = *(const bf16x8*)(&spi[(rowb + l15) * PLSTR_ + j0]);
        }

        f32x4 acc[4];
        #pragma unroll
        for (int tt = 0; tt < 4; ++tt) acc[tt] = (f32x4)0.0f;

        #pragma unroll
        for (int tt = 0; tt < 4; ++tt) {
            const int t = tt * 16 + l15;
            #pragma unroll
            for (int kk = 0; kk < 2; ++kk) {
                const int j0 = kk * 32 + quad * 8;
                const bf16x8 btl = *(const bf16x8*)(tl  + t * 64 + j0);
                const bf16x8 bwr = *(const bf16x8*)(w2r + t * 64 + j0);
                const bf16x8 bwi = *(const bf16x8*)(w2i + t * 64 + j0);
                acc[tt] = __builtin_amdgcn_mfma_f32_16x16x32_bf16(
                    xhi[kk], btl, acc[tt], 0, 0, 0);
                acc[tt] = __builtin_amdgcn_mfma_f32_16x16x32_bf16(
                    xlo[kk], btl, acc[tt], 0, 0, 0);
                acc[tt] = __builtin_amdgcn_mfma_f32_16x16x32_bf16(
                    sr8[kk], bwr, acc[tt], 0, 0, 0);
                acc[tt] = __builtin_amdgcn_mfma_f32_16x16x32_bf16(
                    si8[kk], bwi, acc[tt], 0, 0, 0);
            }
        }

        // store y with relu; lanes 0..15 -> consecutive t (64B segments)
        #pragma unroll
        for (int tt = 0; tt < 4; ++tt)
            #pragma unroll
            for (int r = 0; r < 4; ++r) {
                const int c = half * HC_ + quad * 4 + r;
                const int t = tt * 16 + l15;
                out[((size_t)(b * H_ + h)) * L_ + c * Q_ + t] =
                    fmaxf(acc[tt][r], 0.0f);
            }
    }
}

extern "C" void kernel_launch(void* const* d_in, const int* in_sizes, int n_in,
                              void* d_out, int out_size, void* d_ws, size_t ws_size,
                              hipStream_t stream) {
    const float* x      = (const float*)d_in[0];
    const float* A_real = (const float*)d_in[1];
    const float* A_imag = (const float*)d_in[2];
    const float* Bmat   = (const float*)d_in[3];
    const float* Cmat   = (const float*)d_in[4];
    const float* inv_dt = (const float*)d_in[5];
    float* out = (float*)d_out;

    char* ws = (char*)d_ws;
    unsigned short* W1sr = (unsigned short*)(ws + WS_W1R);
    unsigned short* W1si = (unsigned short*)(ws + WS_W1I);
    unsigned short* TLs  = (unsigned short*)(ws + WS_TL);
    unsigned short* W2sr = (unsigned short*)(ws + WS_W2R);
    unsigned short* W2si = (unsigned short*)(ws + WS_W2I);

    s4d_prep<<<dim3(H_), dim3(64), 0, stream>>>(
        A_real, A_imag, Bmat, Cmat, inv_dt, W1sr, W1si, TLs, W2sr, W2si);
    s4d_fused<<<dim3(H_ * 4), dim3(256), 0, stream>>>(
        x, A_real, A_imag, inv_dt, W1sr, W1si, TLs, W2sr, W2si, out);
}

// Round 9
// 96.322 us; speedup vs baseline: 1.2140x; 1.2140x over previous
//
#include <hip/hip_runtime.h>

// S4D via chunked MFMA reformulation (R8 = R5 fused + wide parallel prep).
//
//  y[c*64+t] = sum_j k[t-j]*x[c*64+j]              (lower-tri Toeplitz, local)
//            + Re( sum_n Ceff2_n w_n^{t+1} S_n[c] ) (carry from prior chunks)
//  S_n[c]    = w^64 * S_n[c-1] + V_n[c-1],  V_n[c] = sum_j w_n^{63-j} x[c*64+j]
//
//  prep (R8): block = h, 256 threads (4 waves). Every matrix element computed
//    in parallel: per-thread exp/sincos start + <=17-step in-thread recurrence
//    (shorter chain than old 64-step serial wave). Stores gathered into
//    16-ushort register tiles -> 2x b128, COALESCED (old W1 stores were
//    64-line scatters). q-table + k reduction via LDS. Also emits Earr=w^64.
//  fused (== R5, best known 105.5us): per (h, b-half) block, 4 waves x 32
//    (b,c) cols; A: MFMA V=X*W1^T -> packed LDS (stride-68, 2-way free);
//    B: reg-prefetched in-LDS scan -> r/i ushort planes (144B rows, aligned
//    b128, <=2-way); C: y = Xhi*TL + Xlo*TL + Sr*W2r + Si*W2i, relu.

#define B_ 8
#define H_ 256
#define N_ 64
#define L_ 2048
#define Q_ 64
#define NC_ 32
#define COLS_ 128
#define PKSTR_ 68      // packed V row stride (uints)
#define PLSTR_ 72      // plane row stride (ushorts); 144 B rows, 16B-aligned

typedef __attribute__((ext_vector_type(8))) short bf16x8;
typedef __attribute__((ext_vector_type(4))) float f32x4;

// ---- ws layout (bytes): 5 bf16 matrices (2 MiB each) + Earr ----
#define WS_W1R  0
#define WS_W1I  (WS_W1R + 2097152)
#define WS_TL   (WS_W1I + 2097152)
#define WS_W2R  (WS_TL  + 2097152)
#define WS_W2I  (WS_W2R + 2097152)
#define WS_E    (WS_W2I + 2097152)    // float2[256*64] = 128 KiB

#if defined(__has_builtin)
#  if __has_builtin(__builtin_amdgcn_cvt_pk_bf16_f32)
#    define HAVE_CVT_PK 1
#  endif
#endif

__device__ __forceinline__ unsigned short bf16_rne(float f) {
    unsigned int u = __float_as_uint(f);
    u += 0x7FFF + ((u >> 16) & 1);
    return (unsigned short)(u >> 16);
}
__device__ __forceinline__ float bf16_to_f(unsigned short h) {
    return __uint_as_float(((unsigned int)h) << 16);
}
// pack two floats to bf16x2 (a -> low, b -> high), RNE
__device__ __forceinline__ unsigned int pack_bf16x2(float a, float b) {
#ifdef HAVE_CVT_PK
    typedef __bf16 bf16v2 __attribute__((ext_vector_type(2)));
    bf16v2 p = __builtin_amdgcn_cvt_pk_bf16_f32(a, b);
    return __builtin_bit_cast(unsigned int, p);
#else
    unsigned int ua = __float_as_uint(a);
    ua += 0x7FFF + ((ua >> 16) & 1);
    unsigned int ub = __float_as_uint(b);
    ub += 0x7FFF + ((ub >> 16) & 1);
    return (ua >> 16) | (ub & 0xFFFF0000u);
#endif
}

// ================= prep (wide): per-h parameter matrices =================
__global__ __launch_bounds__(256) void s4d_prep(
    const float* __restrict__ A_real, const float* __restrict__ A_imag,
    const float* __restrict__ Bmat, const float* __restrict__ Cmat,
    const float* __restrict__ inv_dt,
    unsigned short* __restrict__ W1sr, unsigned short* __restrict__ W1si,
    unsigned short* __restrict__ TLs,
    unsigned short* __restrict__ W2sr, unsigned short* __restrict__ W2si,
    float2* __restrict__ Earr)
{
    __shared__ float qr_l[65 * 66];     // q[m][n] = Re(Ceff2 * w^m)
    __shared__ float qi_l[65 * 66];     // Im(...)
    __shared__ float klds[64];

    const int h   = blockIdx.x;
    const int tid = threadIdx.x;
    const int n   = tid >> 2;           // 0..63
    const int blk = tid & 3;            // 16-element column block
    const int hn  = h * N_ + n;

    // per-n params (computed redundantly by 4 threads; avoids communication)
    const float Ar = -expf(A_real[hn]);     // A = -exp(A_real) - i*A_imag
    const float Ai = -A_imag[hn];
    const float dtv = expf(inv_dt[h]);
    const float dr = dtv * Ar;
    const float di = dtv * Ai;
    const float ew = expf(dr);
    float sdi, cdi;
    sincosf(di, &sdi, &cdi);
    const float wr = ew * cdi;              // w = exp(dt*A)
    const float wi = ew * sdi;
    const float em1r = wr - 1.0f;           // (w-1)/A
    const float em1i = wi;
    const float invden = 1.0f / (Ar * Ar + Ai * Ai);
    const float tr = (em1r * Ar + em1i * Ai) * invden;
    const float ti = (em1i * Ar - em1r * Ai) * invden;
    const float br = Bmat[2 * hn], bi = Bmat[2 * hn + 1];
    const float cr = Cmat[2 * hn], ci = Cmat[2 * hn + 1];
    const float bcr = br * cr - bi * ci;
    const float bci = br * ci + bi * cr;
    const float Cr = 2.0f * (bcr * tr - bci * ti);   // Ceff2 = 2*B*C*(w-1)/A
    const float Ci = 2.0f * (bcr * ti + bci * tr);

    // ---- W1s[n][j] = w^(63-j), j in [16*blk, 16*blk+16) ----
    {
        const int m0 = 48 - 16 * blk;        // lowest m of this j-block
        const float e0 = expf((float)m0 * dr);
        float s0, c0;
        sincosf((float)m0 * di, &s0, &c0);
        float pr = e0 * c0, pi = e0 * s0;    // w^m0
        union { unsigned short u16[16]; uint4 q[2]; } tr_, ti_;
        #pragma unroll
        for (int i = 0; i < 16; ++i) {       // m = m0+i -> local j = 15-i
            tr_.u16[15 - i] = bf16_rne(pr);
            ti_.u16[15 - i] = bf16_rne(pi);
            const float npr = pr * wr - pi * wi;
            pi = pr * wi + pi * wr;
            pr = npr;
        }
        uint4* d0 = (uint4*)(W1sr + (size_t)h * 4096 + n * 64 + blk * 16);
        d0[0] = tr_.q[0]; d0[1] = tr_.q[1];
        uint4* d1 = (uint4*)(W1si + (size_t)h * 4096 + n * 64 + blk * 16);
        d1[0] = ti_.q[0]; d1[1] = ti_.q[1];
    }

    // ---- q table: m in [17*blk, ...) (blk 3 covers 51..64) ----
    {
        const int m0   = blk * 17;
        const int mcnt = (blk == 3) ? 14 : 17;
        const float e0 = expf((float)m0 * dr);
        float s0, c0;
        sincosf((float)m0 * di, &s0, &c0);
        float pr = e0 * c0, pi = e0 * s0;    // w^m0
        for (int i = 0; i < mcnt; ++i) {
            const int m = m0 + i;
            qr_l[m * 66 + n] = Cr * pr - Ci * pi;
            qi_l[m * 66 + n] = Cr * pi + Ci * pr;
            const float npr = pr * wr - pi * wi;
            pi = pr * wi + pi * wr;
            pr = npr;
        }
    }
    __syncthreads();

    // ---- k[t] = sum_n qr[t][n];  Earr[n] = w_n^64 ----
    if (tid < 64) {
        float s = 0.0f;
        for (int j = 0; j < 64; ++j) s += qr_l[tid * 66 + j];
        klds[tid] = s;

        const int hn2 = h * N_ + tid;
        const float Ar2 = -expf(A_real[hn2]);
        const float Ai2 = -A_imag[hn2];
        const float e64 = expf(64.0f * dtv * Ar2);
        float s64, c64;
        sincosf(64.0f * dtv * (-Ai2) * -1.0f, &s64, &c64);  // 64*dt*Ai2
        Earr[hn2] = make_float2(e64 * c64, e64 * s64);
    }
    __syncthreads();

    // ---- TL[t][j] = (j<=t)?k[t-j]:0 and W2[t][n] from q[t+1][n] ----
    {
        const int t = tid >> 2;
        union { unsigned short u16[16]; uint4 q[2]; } a_, b_;
        #pragma unroll
        for (int i = 0; i < 16; ++i) {
            const int j = blk * 16 + i;
            const int d = t - j;
            a_.u16[i] = bf16_rne(d >= 0 ? klds[d >= 0 ? d : 0] : 0.0f);
        }
        uint4* dtl = (uint4*)(TLs + (size_t)h * 4096 + t * 64 + blk * 16);
        dtl[0] = a_.q[0]; dtl[1] = a_.q[1];

        #pragma unroll
        for (int i = 0; i < 16; ++i) {
            const int nn = blk * 16 + i;
            a_.u16[i] = bf16_rne(qr_l[(t + 1) * 66 + nn]);     // Re(Ceff2 w^{t+1})
            b_.u16[i] = bf16_rne(-qi_l[(t + 1) * 66 + nn]);    // -Im(...)
        }
        uint4* d2r = (uint4*)(W2sr + (size_t)h * 4096 + t * 64 + blk * 16);
        d2r[0] = a_.q[0]; d2r[1] = a_.q[1];
        uint4* d2i = (uint4*)(W2si + (size_t)h * 4096 + t * 64 + blk * 16);
        d2i[0] = b_.q[0]; d2i[1] = b_.q[1];
    }
}

// ================= fused (R5): V-GEMM -> in-LDS scan -> y-GEMM =================
__global__ __launch_bounds__(256) void s4d_fused(
    const float* __restrict__ x,
    const float2* __restrict__ Earr,
    const unsigned short* __restrict__ W1sr, const unsigned short* __restrict__ W1si,
    const unsigned short* __restrict__ TLs,
    const unsigned short* __restrict__ W2sr, const unsigned short* __restrict__ W2si,
    float* __restrict__ out)
{
    // packed V (COLS_*68 uints = 34816 B) aliased with state planes
    // (2 * COLS_*72 ushorts = 36864 B); barrier separates the lifetimes.
    __shared__ char smem[COLS_ * PLSTR_ * 2 * 2];
    unsigned int*   vpk = (unsigned int*)smem;
    unsigned short* spr = (unsigned short*)smem;
    unsigned short* spi = (unsigned short*)(smem + COLS_ * PLSTR_ * 2);

    const int h     = blockIdx.x >> 1;
    const int bhalf = blockIdx.x & 1;
    const int lane  = threadIdx.x & 63;
    const int wv    = threadIdx.x >> 6;
    const int colw  = wv * 32;
    const int l15   = lane & 15;
    const int quad  = lane >> 4;

    // ---- x fragments, loaded ONCE (hi/lo bf16 split), reused in A and C ----
    bf16x8 xhi[2][2], xlo[2][2];
    #pragma unroll
    for (int mt = 0; mt < 2; ++mt) {
        const int bc = colw + mt * 16 + l15;
        const int b  = bhalf * 4 + (bc >> 5);
        const int c  = bc & 31;
        const float* xp = x + ((size_t)(b * H_ + h)) * L_ + c * Q_;
        #pragma unroll
        for (int kk = 0; kk < 2; ++kk) {
            const int j0 = kk * 32 + quad * 8;
            const float4 f0 = *(const float4*)(xp + j0);
            const float4 f1 = *(const float4*)(xp + j0 + 4);
            float f[8] = {f0.x, f0.y, f0.z, f0.w, f1.x, f1.y, f1.z, f1.w};
            union { unsigned int u[4]; bf16x8 v; } hi, lo;
            #pragma unroll
            for (int p = 0; p < 4; ++p) {
                const unsigned int hp = pack_bf16x2(f[2 * p], f[2 * p + 1]);
                hi.u[p] = hp;
                const float h0 = __uint_as_float(hp << 16);
                const float h1 = __uint_as_float(hp & 0xFFFF0000u);
                lo.u[p] = pack_bf16x2(f[2 * p] - h0, f[2 * p + 1] - h1);
            }
            xhi[mt][kk] = hi.v;
            xlo[mt][kk] = lo.v;
        }
    }

    // ---- E = w^64 for n = lane (precomputed in prep) ----
    const float2 E = Earr[h * N_ + lane];
    const float Er = E.x, Ei = E.y;

    // ---- phase A: V[(b,c)][n] = X * W1^T (complex) -> packed LDS ----
    {
        const unsigned short* w1r = W1sr + h * 4096;
        const unsigned short* w1i = W1si + h * 4096;

        f32x4 accr[2][4], acci[2][4];
        #pragma unroll
        for (int a = 0; a < 2; ++a)
            #pragma unroll
            for (int b = 0; b < 4; ++b) { accr[a][b] = (f32x4)0.0f; acci[a][b] = (f32x4)0.0f; }

        #pragma unroll
        for (int nt = 0; nt < 4; ++nt) {
            const int n = nt * 16 + l15;
            bf16x8 brf[2], bif[2];
            #pragma unroll
            for (int kk = 0; kk < 2; ++kk) {
                const int j0 = kk * 32 + quad * 8;
                brf[kk] = *(const bf16x8*)(w1r + n * 64 + j0);
                bif[kk] = *(const bf16x8*)(w1i + n * 64 + j0);
            }
            #pragma unroll
            for (int mt = 0; mt < 2; ++mt)
                #pragma unroll
                for (int kk = 0; kk < 2; ++kk) {
                    accr[mt][nt] = __builtin_amdgcn_mfma_f32_16x16x32_bf16(
                        xhi[mt][kk], brf[kk], accr[mt][nt], 0, 0, 0);
                    acci[mt][nt] = __builtin_amdgcn_mfma_f32_16x16x32_bf16(
                        xhi[mt][kk], bif[kk], acci[mt][nt], 0, 0, 0);
                }
        }

        // D layout: row=(quad*4+r) -> bc, col=l15 -> n
        #pragma unroll
        for (int mt = 0; mt < 2; ++mt)
            #pragma unroll
            for (int nt = 0; nt < 4; ++nt)
                #pragma unroll
                for (int r = 0; r < 4; ++r) {
                    const int bc = colw + mt * 16 + quad * 4 + r;
                    const int n  = nt * 16 + l15;
                    vpk[bc * PKSTR_ + n] =
                        pack_bf16x2(accr[mt][nt][r], acci[mt][nt][r]);
                }
    }
    __syncthreads();

    // ---- phase B: prefetch packed V -> barrier -> scan -> state planes ----
    {
        unsigned int vv[NC_];
        const unsigned int* vp = &vpk[(wv * NC_) * PKSTR_ + lane];
        #pragma unroll
        for (int c = 0; c < NC_; ++c) vv[c] = vp[c * PKSTR_];
        __syncthreads();                       // packed lifetime ends

        float sr = 0.0f, si = 0.0f;
        unsigned short* pr = &spr[(wv * NC_) * PLSTR_ + lane];
        unsigned short* pi = &spi[(wv * NC_) * PLSTR_ + lane];
        #pragma unroll
        for (int c = 0; c < NC_; ++c) {
            const float vr = __uint_as_float(vv[c] << 16);
            const float vi = __uint_as_float(vv[c] & 0xFFFF0000u);
            const unsigned int sp2 = pack_bf16x2(sr, si);  // entering state
            pr[c * PLSTR_] = (unsigned short)(sp2 & 0xFFFFu);
            pi[c * PLSTR_] = (unsigned short)(sp2 >> 16);
            const float nsr = fmaf(Er, sr, fmaf(-Ei, si, vr));
            si = fmaf(Ei, sr, fmaf(Er, si, vi));
            sr = nsr;
        }
    }
    __syncthreads();

    // ---- phase C: y = Xhi*TL + Xlo*TL + Sr*W2r + Si*W2i, relu ----
    {
        const unsigned short* tl  = TLs  + h * 4096;
        const unsigned short* w2r = W2sr + h * 4096;
        const unsigned short* w2i = W2si + h * 4096;

        // S fragments: plain b128 reads from planes (A-operand layout)
        bf16x8 sr8[2][2], si8[2][2];
        #pragma unroll
        for (int mt = 0; mt < 2; ++mt) {
            const int bc = colw + mt * 16 + l15;
            #pragma unroll
            for (int kk = 0; kk < 2; ++kk) {
                const int j0 = kk * 32 + quad * 8;
                sr8[mt][kk] = *(const bf16x8*)(&spr[bc * PLSTR_ + j0]);
                si8[mt][kk] = *(const bf16x8*)(&spi[bc * PLSTR_ + j0]);
            }
        }

        f32x4 acc[2][4];
        #pragma unroll
        for (int a = 0; a < 2; ++a)
            #pragma unroll
            for (int t = 0; t < 4; ++t) acc[a][t] = (f32x4)0.0f;

        #pragma unroll
        for (int tt = 0; tt < 4; ++tt) {
            const int t = tt * 16 + l15;
            bf16x8 btl[2], bwr[2], bwi[2];
            #pragma unroll
            for (int kk = 0; kk < 2; ++kk) {
                const int j0 = kk * 32 + quad * 8;
                btl[kk] = *(const bf16x8*)(tl  + t * 64 + j0);
                bwr[kk] = *(const bf16x8*)(w2r + t * 64 + j0);
                bwi[kk] = *(const bf16x8*)(w2i + t * 64 + j0);
            }
            #pragma unroll
            for (int mt = 0; mt < 2; ++mt)
                #pragma unroll
                for (int kk = 0; kk < 2; ++kk) {
                    acc[mt][tt] = __builtin_amdgcn_mfma_f32_16x16x32_bf16(
                        xhi[mt][kk], btl[kk], acc[mt][tt], 0, 0, 0);
                    acc[mt][tt] = __builtin_amdgcn_mfma_f32_16x16x32_bf16(
                        xlo[mt][kk], btl[kk], acc[mt][tt], 0, 0, 0);
                    acc[mt][tt] = __builtin_amdgcn_mfma_f32_16x16x32_bf16(
                        sr8[mt][kk], bwr[kk], acc[mt][tt], 0, 0, 0);
                    acc[mt][tt] = __builtin_amdgcn_mfma_f32_16x16x32_bf16(
                        si8[mt][kk], bwi[kk], acc[mt][tt], 0, 0, 0);
                }
        }

        // store y with relu; lanes 0..15 -> consecutive t (64B segments)
        #pragma unroll
        for (int mt = 0; mt < 2; ++mt)
            #pragma unroll
            for (int tt = 0; tt < 4; ++tt)
                #pragma unroll
                for (int r = 0; r < 4; ++r) {
                    const int bc = colw + mt * 16 + quad * 4 + r;
                    const int b  = bhalf * 4 + (bc >> 5);
                    const int c  = bc & 31;
                    const int t  = tt * 16 + l15;
                    out[((size_t)(b * H_ + h)) * L_ + c * Q_ + t] =
                        fmaxf(acc[mt][tt][r], 0.0f);
                }
    }
}

extern "C" void kernel_launch(void* const* d_in, const int* in_sizes, int n_in,
                              void* d_out, int out_size, void* d_ws, size_t ws_size,
                              hipStream_t stream) {
    const float* x      = (const float*)d_in[0];
    const float* A_real = (const float*)d_in[1];
    const float* A_imag = (const float*)d_in[2];
    const float* Bmat   = (const float*)d_in[3];
    const float* Cmat   = (const float*)d_in[4];
    const float* inv_dt = (const float*)d_in[5];
    float* out = (float*)d_out;

    char* ws = (char*)d_ws;
    unsigned short* W1sr = (unsigned short*)(ws + WS_W1R);
    unsigned short* W1si = (unsigned short*)(ws + WS_W1I);
    unsigned short* TLs  = (unsigned short*)(ws + WS_TL);
    unsigned short* W2sr = (unsigned short*)(ws + WS_W2R);
    unsigned short* W2si = (unsigned short*)(ws + WS_W2I);
    float2*         Earr = (float2*)(ws + WS_E);

    s4d_prep<<<dim3(H_), dim3(256), 0, stream>>>(
        A_real, A_imag, Bmat, Cmat, inv_dt, W1sr, W1si, TLs, W2sr, W2si, Earr);
    s4d_fused<<<dim3(H_ * 2), dim3(256), 0, stream>>>(
        x, Earr, W1sr, W1si, TLs, W2sr, W2si, out);
}

// Round 10
// 90.428 us; speedup vs baseline: 1.2932x; 1.0652x over previous
//
#include <hip/hip_runtime.h>

// S4D via chunked MFMA reformulation (R9 = R8 + LDS-staged W fragments).
//
//  y[c*64+t] = sum_j k[t-j]*x[c*64+j]              (lower-tri Toeplitz, local)
//            + Re( sum_n Ceff2_n w_n^{t+1} S_n[c] ) (carry from prior chunks)
//  S_n[c]    = w^64 * S_n[c-1] + V_n[c-1],  V_n[c] = sum_j w_n^{63-j} x[c*64+j]
//
//  prep (R8): block = h, 256 threads; fully parallel matrix build, coalesced
//    b128 stores; also emits Earr = w^64.
//  fused (R9): per (h, b-half) block, 4 waves x 32 (b,c) cols. NEW: the 5
//    per-h bf16 matrices are staged global->LDS ONCE per block (16B coalesced)
//    and MFMA B-fragments come from ds_read_b128 — removes ~62 MB of
//    redundant per-wave L2 re-reads (R7 showed +82 MB of exactly this
//    traffic cost +11 us). W region rows padded to 72 ushorts (144 B) —
//    identical bank geometry to the phase-C planes running since R5.
//    Region reused: W1r/W1i (phase A) -> TL/W2r/W2i (phase C).
//    A: MFMA V=X*W1^T -> packed LDS (stride-68, 2-way free);
//    B: reg-prefetched in-LDS scan -> r/i ushort planes;
//    C: y = Xhi*TL + Xlo*TL + Sr*W2r + Si*W2i, relu, coalesced store.

#define B_ 8
#define H_ 256
#define N_ 64
#define L_ 2048
#define Q_ 64
#define NC_ 32
#define COLS_ 128
#define PKSTR_ 68      // packed V row stride (uints)
#define PLSTR_ 72      // plane / W-region row stride (ushorts); 144 B rows

typedef __attribute__((ext_vector_type(8))) short bf16x8;
typedef __attribute__((ext_vector_type(4))) float f32x4;

// ---- ws layout (bytes): 5 bf16 matrices (2 MiB each) + Earr ----
#define WS_W1R  0
#define WS_W1I  (WS_W1R + 2097152)
#define WS_TL   (WS_W1I + 2097152)
#define WS_W2R  (WS_TL  + 2097152)
#define WS_W2I  (WS_W2R + 2097152)
#define WS_E    (WS_W2I + 2097152)    // float2[256*64] = 128 KiB

#if defined(__has_builtin)
#  if __has_builtin(__builtin_amdgcn_cvt_pk_bf16_f32)
#    define HAVE_CVT_PK 1
#  endif
#endif

__device__ __forceinline__ unsigned short bf16_rne(float f) {
    unsigned int u = __float_as_uint(f);
    u += 0x7FFF + ((u >> 16) & 1);
    return (unsigned short)(u >> 16);
}
__device__ __forceinline__ float bf16_to_f(unsigned short h) {
    return __uint_as_float(((unsigned int)h) << 16);
}
// pack two floats to bf16x2 (a -> low, b -> high), RNE
__device__ __forceinline__ unsigned int pack_bf16x2(float a, float b) {
#ifdef HAVE_CVT_PK
    typedef __bf16 bf16v2 __attribute__((ext_vector_type(2)));
    bf16v2 p = __builtin_amdgcn_cvt_pk_bf16_f32(a, b);
    return __builtin_bit_cast(unsigned int, p);
#else
    unsigned int ua = __float_as_uint(a);
    ua += 0x7FFF + ((ua >> 16) & 1);
    unsigned int ub = __float_as_uint(b);
    ub += 0x7FFF + ((ub >> 16) & 1);
    return (ua >> 16) | (ub & 0xFFFF0000u);
#endif
}

// ================= prep (wide): per-h parameter matrices =================
__global__ __launch_bounds__(256) void s4d_prep(
    const float* __restrict__ A_real, const float* __restrict__ A_imag,
    const float* __restrict__ Bmat, const float* __restrict__ Cmat,
    const float* __restrict__ inv_dt,
    unsigned short* __restrict__ W1sr, unsigned short* __restrict__ W1si,
    unsigned short* __restrict__ TLs,
    unsigned short* __restrict__ W2sr, unsigned short* __restrict__ W2si,
    float2* __restrict__ Earr)
{
    __shared__ float qr_l[65 * 66];     // q[m][n] = Re(Ceff2 * w^m)
    __shared__ float qi_l[65 * 66];     // Im(...)
    __shared__ float klds[64];

    const int h   = blockIdx.x;
    const int tid = threadIdx.x;
    const int n   = tid >> 2;           // 0..63
    const int blk = tid & 3;            // 16-element column block
    const int hn  = h * N_ + n;

    // per-n params (computed redundantly by 4 threads; avoids communication)
    const float Ar = -expf(A_real[hn]);     // A = -exp(A_real) - i*A_imag
    const float Ai = -A_imag[hn];
    const float dtv = expf(inv_dt[h]);
    const float dr = dtv * Ar;
    const float di = dtv * Ai;
    const float ew = expf(dr);
    float sdi, cdi;
    sincosf(di, &sdi, &cdi);
    const float wr = ew * cdi;              // w = exp(dt*A)
    const float wi = ew * sdi;
    const float em1r = wr - 1.0f;           // (w-1)/A
    const float em1i = wi;
    const float invden = 1.0f / (Ar * Ar + Ai * Ai);
    const float tr = (em1r * Ar + em1i * Ai) * invden;
    const float ti = (em1i * Ar - em1r * Ai) * invden;
    const float br = Bmat[2 * hn], bi = Bmat[2 * hn + 1];
    const float cr = Cmat[2 * hn], ci = Cmat[2 * hn + 1];
    const float bcr = br * cr - bi * ci;
    const float bci = br * ci + bi * cr;
    const float Cr = 2.0f * (bcr * tr - bci * ti);   // Ceff2 = 2*B*C*(w-1)/A
    const float Ci = 2.0f * (bcr * ti + bci * tr);

    // ---- W1s[n][j] = w^(63-j), j in [16*blk, 16*blk+16) ----
    {
        const int m0 = 48 - 16 * blk;        // lowest m of this j-block
        const float e0 = expf((float)m0 * dr);
        float s0, c0;
        sincosf((float)m0 * di, &s0, &c0);
        float pr = e0 * c0, pi = e0 * s0;    // w^m0
        union { unsigned short u16[16]; uint4 q[2]; } tr_, ti_;
        #pragma unroll
        for (int i = 0; i < 16; ++i) {       // m = m0+i -> local j = 15-i
            tr_.u16[15 - i] = bf16_rne(pr);
            ti_.u16[15 - i] = bf16_rne(pi);
            const float npr = pr * wr - pi * wi;
            pi = pr * wi + pi * wr;
            pr = npr;
        }
        uint4* d0 = (uint4*)(W1sr + (size_t)h * 4096 + n * 64 + blk * 16);
        d0[0] = tr_.q[0]; d0[1] = tr_.q[1];
        uint4* d1 = (uint4*)(W1si + (size_t)h * 4096 + n * 64 + blk * 16);
        d1[0] = ti_.q[0]; d1[1] = ti_.q[1];
    }

    // ---- q table: m in [17*blk, ...) (blk 3 covers 51..64) ----
    {
        const int m0   = blk * 17;
        const int mcnt = (blk == 3) ? 14 : 17;
        const float e0 = expf((float)m0 * dr);
        float s0, c0;
        sincosf((float)m0 * di, &s0, &c0);
        float pr = e0 * c0, pi = e0 * s0;    // w^m0
        for (int i = 0; i < mcnt; ++i) {
            const int m = m0 + i;
            qr_l[m * 66 + n] = Cr * pr - Ci * pi;
            qi_l[m * 66 + n] = Cr * pi + Ci * pr;
            const float npr = pr * wr - pi * wi;
            pi = pr * wi + pi * wr;
            pr = npr;
        }
    }
    __syncthreads();

    // ---- k[t] = sum_n qr[t][n];  Earr[n] = w_n^64 ----
    if (tid < 64) {
        float s = 0.0f;
        for (int j = 0; j < 64; ++j) s += qr_l[tid * 66 + j];
        klds[tid] = s;

        const int hn2 = h * N_ + tid;
        const float Ar2 = -expf(A_real[hn2]);
        const float Ai2 = -A_imag[hn2];
        const float e64 = expf(64.0f * dtv * Ar2);
        float s64, c64;
        sincosf(64.0f * dtv * (-Ai2) * -1.0f, &s64, &c64);  // 64*dt*Ai2
        Earr[hn2] = make_float2(e64 * c64, e64 * s64);
    }
    __syncthreads();

    // ---- TL[t][j] = (j<=t)?k[t-j]:0 and W2[t][n] from q[t+1][n] ----
    {
        const int t = tid >> 2;
        union { unsigned short u16[16]; uint4 q[2]; } a_, b_;
        #pragma unroll
        for (int i = 0; i < 16; ++i) {
            const int j = blk * 16 + i;
            const int d = t - j;
            a_.u16[i] = bf16_rne(d >= 0 ? klds[d >= 0 ? d : 0] : 0.0f);
        }
        uint4* dtl = (uint4*)(TLs + (size_t)h * 4096 + t * 64 + blk * 16);
        dtl[0] = a_.q[0]; dtl[1] = a_.q[1];

        #pragma unroll
        for (int i = 0; i < 16; ++i) {
            const int nn = blk * 16 + i;
            a_.u16[i] = bf16_rne(qr_l[(t + 1) * 66 + nn]);     // Re(Ceff2 w^{t+1})
            b_.u16[i] = bf16_rne(-qi_l[(t + 1) * 66 + nn]);    // -Im(...)
        }
        uint4* d2r = (uint4*)(W2sr + (size_t)h * 4096 + t * 64 + blk * 16);
        d2r[0] = a_.q[0]; d2r[1] = a_.q[1];
        uint4* d2i = (uint4*)(W2si + (size_t)h * 4096 + t * 64 + blk * 16);
        d2i[0] = b_.q[0]; d2i[1] = b_.q[1];
    }
}

// ================= fused: staged-W V-GEMM -> in-LDS scan -> y-GEMM =================
__global__ __launch_bounds__(256) void s4d_fused(
    const float* __restrict__ x,
    const float2* __restrict__ Earr,
    const unsigned short* __restrict__ W1sr, const unsigned short* __restrict__ W1si,
    const unsigned short* __restrict__ TLs,
    const unsigned short* __restrict__ W2sr, const unsigned short* __restrict__ W2si,
    float* __restrict__ out)
{
    // 0..36864      : packed V (128x68 uints = 34816 B) ALIASED with the two
    //                 state planes (2 x 128x72 ushorts); barriers separate.
    // 36864..64512  : W region, 3 slots x 64 rows x 72 ushorts (13824 ushorts).
    //                 Phase A: slot0=W1r slot1=W1i; phase C: TL/W2r/W2i.
    __shared__ char smem[64512];
    unsigned int*   vpk  = (unsigned int*)smem;
    unsigned short* spr  = (unsigned short*)smem;
    unsigned short* spi  = (unsigned short*)(smem + COLS_ * PLSTR_ * 2);
    unsigned short* wreg = (unsigned short*)(smem + COLS_ * PLSTR_ * 4);

    const int h     = blockIdx.x >> 1;
    const int bhalf = blockIdx.x & 1;
    const int tid   = threadIdx.x;
    const int lane  = tid & 63;
    const int wv    = tid >> 6;
    const int colw  = wv * 32;
    const int l15   = lane & 15;
    const int quad  = lane >> 4;

    // ---- stage phase-A matrices: W1r -> slot0, W1i -> slot1 (coalesced) ----
    {
        const unsigned short* s0 = W1sr + (size_t)h * 4096;
        const unsigned short* s1 = W1si + (size_t)h * 4096;
        #pragma unroll
        for (int rep = 0; rep < 2; ++rep) {
            const int idx = rep * 256 + tid;
            const int row = idx >> 3, c8 = (idx & 7) * 8;
            *(uint4*)(wreg + row * PLSTR_ + c8) = *(const uint4*)(s0 + idx * 8);
            *(uint4*)(wreg + 4608 + row * PLSTR_ + c8) = *(const uint4*)(s1 + idx * 8);
        }
    }

    // ---- x fragments, loaded ONCE (hi/lo bf16 split), reused in A and C ----
    bf16x8 xhi[2][2], xlo[2][2];
    #pragma unroll
    for (int mt = 0; mt < 2; ++mt) {
        const int bc = colw + mt * 16 + l15;
        const int b  = bhalf * 4 + (bc >> 5);
        const int c  = bc & 31;
        const float* xp = x + ((size_t)(b * H_ + h)) * L_ + c * Q_;
        #pragma unroll
        for (int kk = 0; kk < 2; ++kk) {
            const int j0 = kk * 32 + quad * 8;
            const float4 f0 = *(const float4*)(xp + j0);
            const float4 f1 = *(const float4*)(xp + j0 + 4);
            float f[8] = {f0.x, f0.y, f0.z, f0.w, f1.x, f1.y, f1.z, f1.w};
            union { unsigned int u[4]; bf16x8 v; } hi, lo;
            #pragma unroll
            for (int p = 0; p < 4; ++p) {
                const unsigned int hp = pack_bf16x2(f[2 * p], f[2 * p + 1]);
                hi.u[p] = hp;
                const float h0 = __uint_as_float(hp << 16);
                const float h1 = __uint_as_float(hp & 0xFFFF0000u);
                lo.u[p] = pack_bf16x2(f[2 * p] - h0, f[2 * p + 1] - h1);
            }
            xhi[mt][kk] = hi.v;
            xlo[mt][kk] = lo.v;
        }
    }

    // ---- E = w^64 for n = lane (precomputed in prep) ----
    const float2 E = Earr[h * N_ + lane];
    const float Er = E.x, Ei = E.y;

    __syncthreads();   // W1 staging visible

    // ---- phase A: V[(b,c)][n] = X * W1^T (complex) -> packed LDS ----
    {
        f32x4 accr[2][4], acci[2][4];
        #pragma unroll
        for (int a = 0; a < 2; ++a)
            #pragma unroll
            for (int b = 0; b < 4; ++b) { accr[a][b] = (f32x4)0.0f; acci[a][b] = (f32x4)0.0f; }

        #pragma unroll
        for (int nt = 0; nt < 4; ++nt) {
            const int n = nt * 16 + l15;
            bf16x8 brf[2], bif[2];
            #pragma unroll
            for (int kk = 0; kk < 2; ++kk) {
                const int j0 = kk * 32 + quad * 8;
                brf[kk] = *(const bf16x8*)(wreg + n * PLSTR_ + j0);
                bif[kk] = *(const bf16x8*)(wreg + 4608 + n * PLSTR_ + j0);
            }
            #pragma unroll
            for (int mt = 0; mt < 2; ++mt)
                #pragma unroll
                for (int kk = 0; kk < 2; ++kk) {
                    accr[mt][nt] = __builtin_amdgcn_mfma_f32_16x16x32_bf16(
                        xhi[mt][kk], brf[kk], accr[mt][nt], 0, 0, 0);
                    acci[mt][nt] = __builtin_amdgcn_mfma_f32_16x16x32_bf16(
                        xhi[mt][kk], bif[kk], acci[mt][nt], 0, 0, 0);
                }
        }

        // D layout: row=(quad*4+r) -> bc, col=l15 -> n
        #pragma unroll
        for (int mt = 0; mt < 2; ++mt)
            #pragma unroll
            for (int nt = 0; nt < 4; ++nt)
                #pragma unroll
                for (int r = 0; r < 4; ++r) {
                    const int bc = colw + mt * 16 + quad * 4 + r;
                    const int n  = nt * 16 + l15;
                    vpk[bc * PKSTR_ + n] =
                        pack_bf16x2(accr[mt][nt][r], acci[mt][nt][r]);
                }
    }
    __syncthreads();

    // ---- phase B: prefetch V -> stage TL/W2 -> barrier -> scan -> planes ----
    {
        unsigned int vv[NC_];
        const unsigned int* vp = &vpk[(wv * NC_) * PKSTR_ + lane];
        #pragma unroll
        for (int c = 0; c < NC_; ++c) vv[c] = vp[c * PKSTR_];

        // stage phase-C matrices over the W1 region (all A-reads done)
        {
            const unsigned short* s0 = TLs  + (size_t)h * 4096;
            const unsigned short* s1 = W2sr + (size_t)h * 4096;
            const unsigned short* s2 = W2si + (size_t)h * 4096;
            #pragma unroll
            for (int rep = 0; rep < 2; ++rep) {
                const int idx = rep * 256 + tid;
                const int row = idx >> 3, c8 = (idx & 7) * 8;
                *(uint4*)(wreg + row * PLSTR_ + c8) = *(const uint4*)(s0 + idx * 8);
                *(uint4*)(wreg + 4608 + row * PLSTR_ + c8) = *(const uint4*)(s1 + idx * 8);
                *(uint4*)(wreg + 9216 + row * PLSTR_ + c8) = *(const uint4*)(s2 + idx * 8);
            }
        }
        __syncthreads();                       // packed-V lifetime ends; staging visible

        float sr = 0.0f, si = 0.0f;
        unsigned short* pr = &spr[(wv * NC_) * PLSTR_ + lane];
        unsigned short* pi = &spi[(wv * NC_) * PLSTR_ + lane];
        #pragma unroll
        for (int c = 0; c < NC_; ++c) {
            const float vr = __uint_as_float(vv[c] << 16);
            const float vi = __uint_as_float(vv[c] & 0xFFFF0000u);
            const unsigned int sp2 = pack_bf16x2(sr, si);  // entering state
            pr[c * PLSTR_] = (unsigned short)(sp2 & 0xFFFFu);
            pi[c * PLSTR_] = (unsigned short)(sp2 >> 16);
            const float nsr = fmaf(Er, sr, fmaf(-Ei, si, vr));
            si = fmaf(Ei, sr, fmaf(Er, si, vi));
            sr = nsr;
        }
    }
    __syncthreads();

    // ---- phase C: y = Xhi*TL + Xlo*TL + Sr*W2r + Si*W2i, relu ----
    {
        // S fragments: plain b128 reads from planes (A-operand layout)
        bf16x8 sr8[2][2], si8[2][2];
        #pragma unroll
        for (int mt = 0; mt < 2; ++mt) {
            const int bc = colw + mt * 16 + l15;
            #pragma unroll
            for (int kk = 0; kk < 2; ++kk) {
                const int j0 = kk * 32 + quad * 8;
                sr8[mt][kk] = *(const bf16x8*)(&spr[bc * PLSTR_ + j0]);
                si8[mt][kk] = *(const bf16x8*)(&spi[bc * PLSTR_ + j0]);
            }
        }

        f32x4 acc[2][4];
        #pragma unroll
        for (int a = 0; a < 2; ++a)
            #pragma unroll
            for (int t = 0; t < 4; ++t) acc[a][t] = (f32x4)0.0f;

        #pragma unroll
        for (int tt = 0; tt < 4; ++tt) {
            const int t = tt * 16 + l15;
            bf16x8 btl[2], bwr[2], bwi[2];
            #pragma unroll
            for (int kk = 0; kk < 2; ++kk) {
                const int j0 = kk * 32 + quad * 8;
                btl[kk] = *(const bf16x8*)(wreg + t * PLSTR_ + j0);
                bwr[kk] = *(const bf16x8*)(wreg + 4608 + t * PLSTR_ + j0);
                bwi[kk] = *(const bf16x8*)(wreg + 9216 + t * PLSTR_ + j0);
            }
            #pragma unroll
            for (int mt = 0; mt < 2; ++mt)
                #pragma unroll
                for (int kk = 0; kk < 2; ++kk) {
                    acc[mt][tt] = __builtin_amdgcn_mfma_f32_16x16x32_bf16(
                        xhi[mt][kk], btl[kk], acc[mt][tt], 0, 0, 0);
                    acc[mt][tt] = __builtin_amdgcn_mfma_f32_16x16x32_bf16(
                        xlo[mt][kk], btl[kk], acc[mt][tt], 0, 0, 0);
                    acc[mt][tt] = __builtin_amdgcn_mfma_f32_16x16x32_bf16(
                        sr8[mt][kk], bwr[kk], acc[mt][tt], 0, 0, 0);
                    acc[mt][tt] = __builtin_amdgcn_mfma_f32_16x16x32_bf16(
                        si8[mt][kk], bwi[kk], acc[mt][tt], 0, 0, 0);
                }
        }

        // store y with relu; lanes 0..15 -> consecutive t (64B segments)
        #pragma unroll
        for (int mt = 0; mt < 2; ++mt)
            #pragma unroll
            for (int tt = 0; tt < 4; ++tt)
                #pragma unroll
                for (int r = 0; r < 4; ++r) {
                    const int bc = colw + mt * 16 + quad * 4 + r;
                    const int b  = bhalf * 4 + (bc >> 5);
                    const int c  = bc & 31;
                    const int t  = tt * 16 + l15;
                    out[((size_t)(b * H_ + h)) * L_ + c * Q_ + t] =
                        fmaxf(acc[mt][tt][r], 0.0f);
                }
    }
}

extern "C" void kernel_launch(void* const* d_in, const int* in_sizes, int n_in,
                              void* d_out, int out_size, void* d_ws, size_t ws_size,
                              hipStream_t stream) {
    const float* x      = (const float*)d_in[0];
    const float* A_real = (const float*)d_in[1];
    const float* A_imag = (const float*)d_in[2];
    const float* Bmat   = (const float*)d_in[3];
    const float* Cmat   = (const float*)d_in[4];
    const float* inv_dt = (const float*)d_in[5];
    float* out = (float*)d_out;

    char* ws = (char*)d_ws;
    unsigned short* W1sr = (unsigned short*)(ws + WS_W1R);
    unsigned short* W1si = (unsigned short*)(ws + WS_W1I);
    unsigned short* TLs  = (unsigned short*)(ws + WS_TL);
    unsigned short* W2sr = (unsigned short*)(ws + WS_W2R);
    unsigned short* W2si = (unsigned short*)(ws + WS_W2I);
    float2*         Earr = (float2*)(ws + WS_E);

    s4d_prep<<<dim3(H_), dim3(256), 0, stream>>>(
        A_real, A_imag, Bmat, Cmat, inv_dt, W1sr, W1si, TLs, W2sr, W2si, Earr);
    s4d_fused<<<dim3(H_ * 2), dim3(256), 0, stream>>>(
        x, Earr, W1sr, W1si, TLs, W2sr, W2si, out);
}